// Round 3
// baseline (2656.369 us; speedup 1.0000x reference)
//
#include <hip/hip_runtime.h>
#include <math.h>

#define N_PTS   8192
#define KNN     30
#define CAP     30      // per-lane buffer slots (== KNN: union is always a superset of top-30)
#define GROUPS  16      // queries per block
#define BLOCK   128     // 8 lanes per query
#define TILE    256     // candidate points staged per LDS tile

// ---------------------------------------------------------------------------
// Prep: x (4,3,8192) -> pts[b][i] = {x,y,z, xx_np}; copy x into out ch 0..2.
// xx_np replicates numpy: rn(rn(rn(x^2)+rn(y^2))+rn(z^2))  (no fma!)
// ---------------------------------------------------------------------------
__global__ __launch_bounds__(256) void prep_kernel(const float* __restrict__ x,
                                                   float4* __restrict__ pts,
                                                   float* __restrict__ out) {
    int gid = blockIdx.x * 256 + threadIdx.x;       // 0..32767
    int b = gid >> 13;
    int i = gid & (N_PTS - 1);
    const float* xb = x + (size_t)b * 3 * N_PTS;
    float px = xb[i];
    float py = xb[N_PTS + i];
    float pz = xb[2 * N_PTS + i];
    float xx = __fadd_rn(__fadd_rn(__fmul_rn(px, px), __fmul_rn(py, py)), __fmul_rn(pz, pz));
    pts[gid] = make_float4(px, py, pz, xx);
    float* ob = out + (size_t)b * 6 * N_PTS;
    ob[i]             = px;
    ob[N_PTS + i]     = py;
    ob[2 * N_PTS + i] = pz;
}

// ---------------------------------------------------------------------------
// Main: 8 lanes/query. Selection metric = bitwise numpy-fp32 pairwise:
//   mm = fmaf(z,z, fmaf(y,y, rn(x*x)))   (sgemm ascending-k fma chain)
//   d  = rn( rn(xx_i + xx_j) - rn(2*mm) )
// Radius-filtered scan + per-lane top-30 + group-union lex rank (stable ties).
// ---------------------------------------------------------------------------
__global__ __launch_bounds__(BLOCK) void knn_normal_kernel(const float4* __restrict__ pts,
                                                           float* __restrict__ out) {
    __shared__ float  bufd[CAP][BLOCK];
    __shared__ int    bufi[CAP][BLOCK];
    __shared__ float4 lpts[TILE];

    const int t   = threadIdx.x;
    const int l8  = t & 7;
    const int gb  = t & ~7;
    const int qid = blockIdx.x * GROUPS + (t >> 3);
    const int b   = qid >> 13;
    const int i   = qid & (N_PTS - 1);
    const float4* __restrict__ P = pts + ((size_t)b << 13);
    const float4 qp = P[i];

    // ---- analytic radius: lambda(r) = 2178.8 * exp(-rho^2/2) * r^3 = 52 ----
    const float Acoef = 0.023866f;        // 52 / 2178.8
    float rho = sqrtf(qp.w);
    float r = fminf(cbrtf(Acoef * __expf(0.5f * rho * rho)), 1.3f);
    float rm = rho + 0.5f * r;
    r = fminf(cbrtf(Acoef * __expf(0.5f * rm * rm)), 1.3f);
    rm = rho + 0.5f * r;
    r = fminf(cbrtf(Acoef * __expf(0.5f * rm * rm)), 1.3f);
    r *= 1.05f;                           // safety
    float r2     = r * r;
    float r2prev = -3.0e38f;              // first pass accepts everything <= r2

    int   cnt = 0, found = 0;
    float mxd = 0.f;                      // lane lex-max, valid once cnt == CAP
    int   mxi = 0, mslot = 0;
    bool  active = true;

    for (;;) {
        for (int tb = 0; tb < N_PTS; tb += TILE) {
            __syncthreads();
            for (int k = t; k < TILE; k += BLOCK) lpts[k] = P[tb + k];
            __syncthreads();
            if (!active) continue;
            for (int s = 0; s < TILE / 8; ++s) {
                int jl = (s << 3) | l8;
                float4 p = lpts[jl];
                // bitwise numpy-fp32 pairwise distance
                float mm = __fmaf_rn(qp.z, p.z, __fmaf_rn(qp.y, p.y, __fmul_rn(qp.x, p.x)));
                float d  = __fsub_rn(__fadd_rn(qp.w, p.w), __fmul_rn(2.0f, mm));
                if (d <= r2 && d > r2prev) {
                    ++found;
                    int j = tb + jl;
                    if (cnt < CAP) {
                        bufd[cnt][t] = d; bufi[cnt][t] = j; ++cnt;
                        if (cnt == CAP) {
                            mxd = -3.0e38f; mxi = -1; mslot = 0;
                            #pragma unroll
                            for (int u = 0; u < CAP; ++u) {
                                float dd = bufd[u][t]; int ii = bufi[u][t];
                                if (dd > mxd || (dd == mxd && ii > mxi)) { mxd = dd; mxi = ii; mslot = u; }
                            }
                        }
                    } else if (d < mxd || (d == mxd && j < mxi)) {
                        bufd[mslot][t] = d; bufi[mslot][t] = j;
                        mxd = -3.0e38f; mxi = -1; mslot = 0;
                        #pragma unroll
                        for (int u = 0; u < CAP; ++u) {
                            float dd = bufd[u][t]; int ii = bufi[u][t];
                            if (dd > mxd || (dd == mxd && ii > mxi)) { mxd = dd; mxi = ii; mslot = u; }
                        }
                    }
                }
            }
        }
        int tot = found;
        tot += __shfl_xor(tot, 1, 8);
        tot += __shfl_xor(tot, 2, 8);
        tot += __shfl_xor(tot, 4, 8);
        int need = (active && tot < KNN) ? 1 : 0;
        if (!__syncthreads_or(need)) break;   // block-uniform exit (barrier)
        active = (need != 0);                 // satisfied groups stop appending
        r2prev = r2;
        r2 *= 2.5f;
    }

    // ---- exact stable top-30 via lex (d, idx) rank against the group union ----
    int cvec[8];
    #pragma unroll
    for (int l2 = 0; l2 < 8; ++l2) cvec[l2] = __shfl(cnt, l2, 8);

    const double qx = (double)qp.x, qy = (double)qp.y, qz = (double)qp.z;
    double sx = 0.0, sy = 0.0, sz = 0.0;
    double sxx = 0.0, sxy = 0.0, sxz = 0.0, syy = 0.0, syz = 0.0, szz = 0.0;

    for (int s0 = 0; s0 < cnt; ++s0) {
        float d  = bufd[s0][t];
        int   idx = bufi[s0][t];
        int rank = 0;
        #pragma unroll
        for (int l2 = 0; l2 < 8; ++l2) {
            int c2  = cvec[l2];
            int col = gb + l2;
            for (int u = 0; u < c2; ++u) {
                float d2 = bufd[u][col];
                int   i2 = bufi[u][col];
                rank += (d2 < d || (d2 == d && i2 < idx)) ? 1 : 0;
            }
        }
        if (rank < KNN) {   // exactly 30 survivors across the group (stable ties)
            float4 p = P[idx];
            double ax = (double)p.x - qx, ay = (double)p.y - qy, az = (double)p.z - qz;
            sx += ax; sy += ay; sz += az;
            sxx = fma(ax, ax, sxx); sxy = fma(ax, ay, sxy); sxz = fma(ax, az, sxz);
            syy = fma(ay, ay, syy); syz = fma(ay, az, syz); szz = fma(az, az, szz);
        }
    }

    // ---- reduce 9 fp64 sums across the 8-lane group ----
    #pragma unroll
    for (int off = 1; off < 8; off <<= 1) {
        sx  += __shfl_xor(sx,  off, 8); sy  += __shfl_xor(sy,  off, 8); sz  += __shfl_xor(sz,  off, 8);
        sxx += __shfl_xor(sxx, off, 8); sxy += __shfl_xor(sxy, off, 8); sxz += __shfl_xor(sxz, off, 8);
        syy += __shfl_xor(syy, off, 8); syz += __shfl_xor(syz, off, 8); szz += __shfl_xor(szz, off, 8);
    }

    if (l8 == 0) {
        const double kinv = 1.0 / (double)KNN;
        double m00 = sxx - sx * sx * kinv;
        double m11 = syy - sy * sy * kinv;
        double m22 = szz - sz * sz * kinv;
        double m01 = sxy - sx * sy * kinv;
        double m02 = sxz - sx * sz * kinv;
        double m12 = syz - sy * sz * kinv;

        double nx = 1.0, ny = 0.0, nz = 0.0;
        double q3 = (m00 + m11 + m22) / 3.0;
        double p1 = m01 * m01 + m02 * m02 + m12 * m12;
        double d00 = m00 - q3, d11 = m11 - q3, d22 = m22 - q3;
        double p2 = d00 * d00 + d11 * d11 + d22 * d22 + 2.0 * p1;
        if (p2 > 1e-280) {
            double pp = sqrt(p2 / 6.0);
            double ip = 1.0 / pp;
            double b00 = d00 * ip, b11 = d11 * ip, b22 = d22 * ip;
            double b01 = m01 * ip, b02 = m02 * ip, b12 = m12 * ip;
            double detB = b00 * (b11 * b22 - b12 * b12)
                        - b01 * (b01 * b22 - b12 * b02)
                        + b02 * (b01 * b12 - b11 * b02);
            double rr = 0.5 * detB;
            rr = rr < -1.0 ? -1.0 : (rr > 1.0 ? 1.0 : rr);
            double phi = acos(rr) / 3.0;
            double lam = q3 + 2.0 * pp * cos(phi + 2.0943951023931953); // smallest eig
            double a00 = m00 - lam, a11 = m11 - lam, a22 = m22 - lam;
            double v0x = m01 * m12 - m02 * a11, v0y = m02 * m01 - a00 * m12, v0z = a00 * a11 - m01 * m01;
            double v1x = m01 * a22 - m02 * m12, v1y = m02 * m02 - a00 * a22, v1z = a00 * m12 - m01 * m02;
            double v2x = a11 * a22 - m12 * m12, v2y = m12 * m02 - m01 * a22, v2z = m01 * m12 - a11 * m02;
            double n0 = v0x * v0x + v0y * v0y + v0z * v0z;
            double n1 = v1x * v1x + v1y * v1y + v1z * v1z;
            double n2 = v2x * v2x + v2y * v2y + v2z * v2z;
            double bx = v0x, by = v0y, bz = v0z, bn = n0;
            if (n1 > bn) { bx = v1x; by = v1y; bz = v1z; bn = n1; }
            if (n2 > bn) { bx = v2x; by = v2y; bz = v2z; bn = n2; }
            if (bn > 1e-280) {
                double inv = 1.0 / sqrt(bn);
                nx = bx * inv; ny = by * inv; nz = bz * inv;
            }
        }
        double dq = -(qx * nx + qy * ny + qz * nz);
        if (dq < 0.0) { nx = -nx; ny = -ny; nz = -nz; }

        float* ob = out + (size_t)b * 6 * N_PTS;
        ob[3 * N_PTS + i] = (float)nx;
        ob[4 * N_PTS + i] = (float)ny;
        ob[5 * N_PTS + i] = (float)nz;
    }
}

// ---------------------------------------------------------------------------
extern "C" void kernel_launch(void* const* d_in, const int* in_sizes, int n_in,
                              void* d_out, int out_size, void* d_ws, size_t ws_size,
                              hipStream_t stream) {
    const float* x = (const float*)d_in[0];
    float* out = (float*)d_out;
    float4* pts = (float4*)d_ws;   // 32768 * 16 B = 512 KB scratch

    prep_kernel<<<dim3(32768 / 256), dim3(256), 0, stream>>>(x, pts, out);
    knn_normal_kernel<<<dim3(32768 / GROUPS), dim3(BLOCK), 0, stream>>>(pts, out);
}

// Round 4
// 932.051 us; speedup vs baseline: 2.8500x; 2.8500x over previous
//
#include <hip/hip_runtime.h>
#include <math.h>

#define N_PTS   8192
#define KNN     30
#define CAP     30      // per-lane buffer slots (== KNN: union is always a superset of top-30)
#define GROUPS  8       // queries per block (8 lanes per query)
#define BLOCK   64      // one wave per block

// ---------------------------------------------------------------------------
// Prep: x (4,3,8192) -> pts[b][i] = {x,y,z, xx_np}; copy x into out ch 0..2.
// xx_np replicates numpy: rn(rn(rn(x^2)+rn(y^2))+rn(z^2))  (no fma!)
// ---------------------------------------------------------------------------
__global__ __launch_bounds__(256) void prep_kernel(const float* __restrict__ x,
                                                   float4* __restrict__ pts,
                                                   float* __restrict__ out) {
    int gid = blockIdx.x * 256 + threadIdx.x;       // 0..32767
    int b = gid >> 13;
    int i = gid & (N_PTS - 1);
    const float* xb = x + (size_t)b * 3 * N_PTS;
    float px = xb[i];
    float py = xb[N_PTS + i];
    float pz = xb[2 * N_PTS + i];
    float xx = __fadd_rn(__fadd_rn(__fmul_rn(px, px), __fmul_rn(py, py)), __fmul_rn(pz, pz));
    pts[gid] = make_float4(px, py, pz, xx);
    float* ob = out + (size_t)b * 6 * N_PTS;
    ob[i]             = px;
    ob[N_PTS + i]     = py;
    ob[2 * N_PTS + i] = pz;
}

// ---------------------------------------------------------------------------
// Main: one wave per block, 8 lanes/query. Barrier-free global-load scan with
// numpy-fp32-bitwise metric; quadrature-exact radius; per-group rescan; union
// lex-rank selection; fp64 cov + eigen epilogue.
// ---------------------------------------------------------------------------
__global__ __launch_bounds__(BLOCK) void knn_normal_kernel(const float4* __restrict__ pts,
                                                           float* __restrict__ out) {
    __shared__ float  bufd[CAP][BLOCK];
    __shared__ int    bufi[CAP][BLOCK];

    const int t   = threadIdx.x;          // 0..63
    const int l8  = t & 7;
    const int gb  = t & ~7;
    const int qid = blockIdx.x * GROUPS + (t >> 3);
    const int b   = qid >> 13;
    const int i   = qid & (N_PTS - 1);
    const float4* __restrict__ P = pts + ((size_t)b << 13);
    const float4 qp = P[i];

    // ---- radius: solve lambda(r) = 55 where lambda = Gaussian mass of ball(c, r)
    //      lambda(r) = 520.1 * 2*pi * Int_{max(0,c-r)}^{c+r} e^{-s^2/2} * s * h(s) ds,
    //      h(s) = min((r^2-(c-s)^2)/(2c), 2s)     (Simpson-12 + 18-step bisection)
    const float c = fmaxf(sqrtf(qp.w), 1e-3f);
    float rlo = 0.05f, rhi = 6.0f;
    for (int it = 0; it < 18; ++it) {
        float r = 0.5f * (rlo + rhi);
        float slo = fmaxf(c - r, 0.0f), shi = c + r;
        float hstep = (shi - slo) * (1.0f / 12.0f);
        float acc = 0.0f;
        #pragma unroll
        for (int k = 0; k <= 12; ++k) {
            float s  = slo + hstep * (float)k;
            float cs = c - s;
            float hh = fminf((r * r - cs * cs) * (0.5f / c), 2.0f * s);
            hh = fmaxf(hh, 0.0f);
            float f = __expf(-0.5f * s * s) * s * hh;
            float w = (k == 0 || k == 12) ? 1.0f : ((k & 1) ? 4.0f : 2.0f);
            acc = fmaf(w, f, acc);
        }
        float lam = 1089.3f * acc * hstep;   // 520.1 * 2*pi / 3
        if (lam < 55.0f) rlo = r; else rhi = r;
    }
    float rad = rhi * 1.02f;                 // safety
    float r2     = rad * rad;
    float r2prev = -3.0e38f;                 // first pass accepts everything <= r2

    int   cnt = 0, found = 0;
    float mxd = 0.f;                         // lane lex-max, valid once cnt == CAP
    int   mxi = 0, mslot = 0;
    bool  active = true;

    for (;;) {
        if (active) {
            #pragma unroll 4
            for (int s = 0; s < N_PTS / 8; ++s) {
                int j = (s << 3) | l8;
                float4 p = P[j];             // wave touches ONE 128B line per iter
                // bitwise numpy-fp32 pairwise distance
                float mm = __fmaf_rn(qp.z, p.z, __fmaf_rn(qp.y, p.y, __fmul_rn(qp.x, p.x)));
                float d  = __fsub_rn(__fadd_rn(qp.w, p.w), __fmul_rn(2.0f, mm));
                if (d <= r2 && d > r2prev) {
                    ++found;
                    if (cnt < CAP) {
                        bufd[cnt][t] = d; bufi[cnt][t] = j; ++cnt;
                        if (cnt == CAP) {
                            mxd = -3.0e38f; mxi = -1; mslot = 0;
                            #pragma unroll
                            for (int u = 0; u < CAP; ++u) {
                                float dd = bufd[u][t]; int ii = bufi[u][t];
                                if (dd > mxd || (dd == mxd && ii > mxi)) { mxd = dd; mxi = ii; mslot = u; }
                            }
                        }
                    } else if (d < mxd || (d == mxd && j < mxi)) {
                        bufd[mslot][t] = d; bufi[mslot][t] = j;
                        mxd = -3.0e38f; mxi = -1; mslot = 0;
                        #pragma unroll
                        for (int u = 0; u < CAP; ++u) {
                            float dd = bufd[u][t]; int ii = bufi[u][t];
                            if (dd > mxd || (dd == mxd && ii > mxi)) { mxd = dd; mxi = ii; mslot = u; }
                        }
                    }
                }
            }
        }
        int tot = found;
        tot += __shfl_xor(tot, 1, 8);
        tot += __shfl_xor(tot, 2, 8);
        tot += __shfl_xor(tot, 4, 8);
        bool need = active && (tot < KNN);
        if (__ballot(need) == 0ULL) break;   // wave-uniform exit, no barrier
        active = need;                       // only needy groups rescan (exec-masked)
        r2prev = r2;
        r2 *= 2.5f;
    }
    __syncthreads();                         // LDS visibility scan -> rank (1 wave)

    // ---- exact stable top-30 via lex (d, idx) rank against the group union ----
    int cvec[8];
    #pragma unroll
    for (int l2 = 0; l2 < 8; ++l2) cvec[l2] = __shfl(cnt, l2, 8);

    const double qx = (double)qp.x, qy = (double)qp.y, qz = (double)qp.z;
    double sx = 0.0, sy = 0.0, sz = 0.0;
    double sxx = 0.0, sxy = 0.0, sxz = 0.0, syy = 0.0, syz = 0.0, szz = 0.0;

    for (int s0 = 0; s0 < cnt; ++s0) {
        float d   = bufd[s0][t];
        int   idx = bufi[s0][t];
        int rank = 0;
        #pragma unroll
        for (int l2 = 0; l2 < 8; ++l2) {
            int c2  = cvec[l2];
            int col = gb + l2;
            for (int u = 0; u < c2; ++u) {
                float d2 = bufd[u][col];
                int   i2 = bufi[u][col];
                rank += (d2 < d || (d2 == d && i2 < idx)) ? 1 : 0;
            }
        }
        if (rank < KNN) {   // exactly 30 survivors across the group (stable ties)
            float4 p = P[idx];
            double ax = (double)p.x - qx, ay = (double)p.y - qy, az = (double)p.z - qz;
            sx += ax; sy += ay; sz += az;
            sxx = fma(ax, ax, sxx); sxy = fma(ax, ay, sxy); sxz = fma(ax, az, sxz);
            syy = fma(ay, ay, syy); syz = fma(ay, az, syz); szz = fma(az, az, szz);
        }
    }

    // ---- reduce 9 fp64 sums across the 8-lane group ----
    #pragma unroll
    for (int off = 1; off < 8; off <<= 1) {
        sx  += __shfl_xor(sx,  off, 8); sy  += __shfl_xor(sy,  off, 8); sz  += __shfl_xor(sz,  off, 8);
        sxx += __shfl_xor(sxx, off, 8); sxy += __shfl_xor(sxy, off, 8); sxz += __shfl_xor(sxz, off, 8);
        syy += __shfl_xor(syy, off, 8); syz += __shfl_xor(syz, off, 8); szz += __shfl_xor(szz, off, 8);
    }

    if (l8 == 0) {
        const double kinv = 1.0 / (double)KNN;
        double m00 = sxx - sx * sx * kinv;
        double m11 = syy - sy * sy * kinv;
        double m22 = szz - sz * sz * kinv;
        double m01 = sxy - sx * sy * kinv;
        double m02 = sxz - sx * sz * kinv;
        double m12 = syz - sy * sz * kinv;

        double nx = 1.0, ny = 0.0, nz = 0.0;
        double q3 = (m00 + m11 + m22) / 3.0;
        double p1 = m01 * m01 + m02 * m02 + m12 * m12;
        double d00 = m00 - q3, d11 = m11 - q3, d22 = m22 - q3;
        double p2 = d00 * d00 + d11 * d11 + d22 * d22 + 2.0 * p1;
        if (p2 > 1e-280) {
            double pp = sqrt(p2 / 6.0);
            double ip = 1.0 / pp;
            double b00 = d00 * ip, b11 = d11 * ip, b22 = d22 * ip;
            double b01 = m01 * ip, b02 = m02 * ip, b12 = m12 * ip;
            double detB = b00 * (b11 * b22 - b12 * b12)
                        - b01 * (b01 * b22 - b12 * b02)
                        + b02 * (b01 * b12 - b11 * b02);
            double rr = 0.5 * detB;
            rr = rr < -1.0 ? -1.0 : (rr > 1.0 ? 1.0 : rr);
            double phi = acos(rr) / 3.0;
            double lam = q3 + 2.0 * pp * cos(phi + 2.0943951023931953); // smallest eig
            double a00 = m00 - lam, a11 = m11 - lam, a22 = m22 - lam;
            double v0x = m01 * m12 - m02 * a11, v0y = m02 * m01 - a00 * m12, v0z = a00 * a11 - m01 * m01;
            double v1x = m01 * a22 - m02 * m12, v1y = m02 * m02 - a00 * a22, v1z = a00 * m12 - m01 * m02;
            double v2x = a11 * a22 - m12 * m12, v2y = m12 * m02 - m01 * a22, v2z = m01 * m12 - a11 * m02;
            double n0 = v0x * v0x + v0y * v0y + v0z * v0z;
            double n1 = v1x * v1x + v1y * v1y + v1z * v1z;
            double n2 = v2x * v2x + v2y * v2y + v2z * v2z;
            double bx = v0x, by = v0y, bz = v0z, bn = n0;
            if (n1 > bn) { bx = v1x; by = v1y; bz = v1z; bn = n1; }
            if (n2 > bn) { bx = v2x; by = v2y; bz = v2z; bn = n2; }
            if (bn > 1e-280) {
                double inv = 1.0 / sqrt(bn);
                nx = bx * inv; ny = by * inv; nz = bz * inv;
            }
        }
        double dq = -(qx * nx + qy * ny + qz * nz);
        if (dq < 0.0) { nx = -nx; ny = -ny; nz = -nz; }

        float* ob = out + (size_t)b * 6 * N_PTS;
        ob[3 * N_PTS + i] = (float)nx;
        ob[4 * N_PTS + i] = (float)ny;
        ob[5 * N_PTS + i] = (float)nz;
    }
}

// ---------------------------------------------------------------------------
extern "C" void kernel_launch(void* const* d_in, const int* in_sizes, int n_in,
                              void* d_out, int out_size, void* d_ws, size_t ws_size,
                              hipStream_t stream) {
    const float* x = (const float*)d_in[0];
    float* out = (float*)d_out;
    float4* pts = (float4*)d_ws;   // 32768 * 16 B = 512 KB scratch

    prep_kernel<<<dim3(32768 / 256), dim3(256), 0, stream>>>(x, pts, out);
    knn_normal_kernel<<<dim3(32768 / GROUPS), dim3(BLOCK), 0, stream>>>(pts, out);
}

// Round 5
// 520.013 us; speedup vs baseline: 5.1083x; 1.7924x over previous
//
#include <hip/hip_runtime.h>
#include <math.h>

#define N_PTS   8192
#define KNN     30
#define CAPG    160     // max stored candidates per group
#define STR     161     // LDS row stride (odd -> 8 groups hit 8 distinct banks)
#define GROUPS  8       // queries per block (8 lanes per query)
#define BLOCK   64      // one wave per block

// ---------------------------------------------------------------------------
// Prep: x (4,3,8192) -> pts[b][i] = {x,y,z, xx_np}; copy x into out ch 0..2.
// xx_np replicates numpy: rn(rn(rn(x^2)+rn(y^2))+rn(z^2))  (no fma!)
// ---------------------------------------------------------------------------
__global__ __launch_bounds__(256) void prep_kernel(const float* __restrict__ x,
                                                   float4* __restrict__ pts,
                                                   float* __restrict__ out) {
    int gid = blockIdx.x * 256 + threadIdx.x;       // 0..32767
    int b = gid >> 13;
    int i = gid & (N_PTS - 1);
    const float* xb = x + (size_t)b * 3 * N_PTS;
    float px = xb[i];
    float py = xb[N_PTS + i];
    float pz = xb[2 * N_PTS + i];
    float xx = __fadd_rn(__fadd_rn(__fmul_rn(px, px), __fmul_rn(py, py)), __fmul_rn(pz, pz));
    pts[gid] = make_float4(px, py, pz, xx);
    float* ob = out + (size_t)b * 6 * N_PTS;
    ob[i]             = px;
    ob[N_PTS + i]     = py;
    ob[2 * N_PTS + i] = pz;
}

// ---------------------------------------------------------------------------
// Main: one wave per block, 8 lanes/query. Branch-free ballot-compaction scan
// (bitwise numpy-fp32 metric) into per-group LDS lists; rank-in-list stable
// top-30; fp64 cov + closed-form eigensolve.
// ---------------------------------------------------------------------------
__global__ __launch_bounds__(BLOCK) void knn_normal_kernel(const float4* __restrict__ pts,
                                                           float* __restrict__ out) {
    __shared__ float lds_d[GROUPS * STR];
    __shared__ int   lds_i[GROUPS * STR];

    const int t   = threadIdx.x;          // 0..63
    const int l8  = t & 7;
    const int g   = t >> 3;
    const int gb  = t & ~7;               // ballot shift for this group
    const int qid = blockIdx.x * GROUPS + g;
    const int b   = qid >> 13;
    const int i   = qid & (N_PTS - 1);
    const float4* __restrict__ P = pts + ((size_t)b << 13);
    const float4 qp = P[i];

    float* __restrict__ ldg = lds_d + g * STR;
    int*   __restrict__ lig = lds_i + g * STR;

    // ---- radius: solve lambda(r) = 55, lambda = Gaussian mass of ball(c,r)
    //      (Simpson-8 quadrature + 14-step bisection; rescan is the safety net)
    const float c = fmaxf(sqrtf(qp.w), 1e-3f);
    float rlo = 0.05f, rhi = 6.0f;
    for (int it = 0; it < 14; ++it) {
        float r = 0.5f * (rlo + rhi);
        float slo = fmaxf(c - r, 0.0f), shi = c + r;
        float h = (shi - slo) * 0.125f;
        float acc = 0.0f;
        #pragma unroll
        for (int k = 0; k <= 8; ++k) {
            float s  = slo + h * (float)k;
            float cs = c - s;
            float hh = fmaxf(fminf((r * r - cs * cs) * (0.5f / c), 2.0f * s), 0.0f);
            float f = __expf(-0.5f * s * s) * s * hh;
            float w = (k == 0 || k == 8) ? 1.0f : ((k & 1) ? 4.0f : 2.0f);
            acc = fmaf(w, f, acc);
        }
        float lam = 1089.3f * acc * h;    // 520.1 * 2*pi / 3
        if (lam < 55.0f) rlo = r; else rhi = r;
    }
    float rad = rhi * 1.02f;
    float r2  = rad * rad;

    int  cnt = 0;
    bool active = true;

    for (;;) {
        if (active) {
            cnt = 0;
            #pragma unroll 8
            for (int s = 0; s < N_PTS / 8; ++s) {
                int j = (s << 3) | l8;
                float4 p = P[j];          // one 128B line per wave-iter (8-way bcast)
                // bitwise numpy-fp32 pairwise distance
                float mm = __fmaf_rn(qp.z, p.z, __fmaf_rn(qp.y, p.y, __fmul_rn(qp.x, p.x)));
                float d  = __fsub_rn(__fadd_rn(qp.w, p.w), __fmul_rn(2.0f, mm));
                bool hit = (d <= r2);
                unsigned long long m = __ballot(hit);
                unsigned sub = (unsigned)((m >> gb) & 0xFFull);
                if (hit) {
                    int slot = cnt + __popc(sub & ((1u << l8) - 1u));
                    if (slot < CAPG) { ldg[slot] = d; lig[slot] = j; }
                }
                cnt += __popc(sub);       // group-uniform
            }
        }
        bool bad = active && (cnt < KNN || cnt > CAPG);
        if (__ballot(bad) == 0ULL) break;   // wave-uniform exit
        active = bad;                       // only bad groups rescan (exec-masked)
        if (active) r2 = (cnt < KNN) ? r2 * 1.6f : r2 * 0.82f;
    }
    __syncthreads();                        // LDS visibility (single wave: cheap)

    // ---- stable top-30: rank within the group list (idx-sorted by construction,
    //      so tie-break by list position == lowest index). Only d-array is read:
    //      broadcast within group, 8 distinct banks across groups (STR=161).
    const double qx = (double)qp.x, qy = (double)qp.y, qz = (double)qp.z;
    double sx = 0.0, sy = 0.0, sz = 0.0;
    double sxx = 0.0, sxy = 0.0, sxz = 0.0, syy = 0.0, syz = 0.0, szz = 0.0;

    for (int k = l8; k < cnt; k += 8) {
        float d = ldg[k];
        int rank = 0;
        for (int u = 0; u < cnt; ++u) {
            float d2 = ldg[u];
            rank += (d2 < d || (d2 == d && u < k)) ? 1 : 0;
        }
        if (rank < KNN) {                   // exactly 30 survivors per group
            int idx = lig[k];
            float4 p = P[idx];
            double ax = (double)p.x - qx, ay = (double)p.y - qy, az = (double)p.z - qz;
            sx += ax; sy += ay; sz += az;
            sxx = fma(ax, ax, sxx); sxy = fma(ax, ay, sxy); sxz = fma(ax, az, sxz);
            syy = fma(ay, ay, syy); syz = fma(ay, az, syz); szz = fma(az, az, szz);
        }
    }

    // ---- reduce 9 fp64 sums across the 8-lane group ----
    #pragma unroll
    for (int off = 1; off < 8; off <<= 1) {
        sx  += __shfl_xor(sx,  off, 8); sy  += __shfl_xor(sy,  off, 8); sz  += __shfl_xor(sz,  off, 8);
        sxx += __shfl_xor(sxx, off, 8); sxy += __shfl_xor(sxy, off, 8); sxz += __shfl_xor(sxz, off, 8);
        syy += __shfl_xor(syy, off, 8); syz += __shfl_xor(syz, off, 8); szz += __shfl_xor(szz, off, 8);
    }

    if (l8 == 0) {
        const double kinv = 1.0 / (double)KNN;
        double m00 = sxx - sx * sx * kinv;
        double m11 = syy - sy * sy * kinv;
        double m22 = szz - sz * sz * kinv;
        double m01 = sxy - sx * sy * kinv;
        double m02 = sxz - sx * sz * kinv;
        double m12 = syz - sy * sz * kinv;

        double nx = 1.0, ny = 0.0, nz = 0.0;
        double q3 = (m00 + m11 + m22) / 3.0;
        double p1 = m01 * m01 + m02 * m02 + m12 * m12;
        double d00 = m00 - q3, d11 = m11 - q3, d22 = m22 - q3;
        double p2 = d00 * d00 + d11 * d11 + d22 * d22 + 2.0 * p1;
        if (p2 > 1e-280) {
            double pp = sqrt(p2 / 6.0);
            double ip = 1.0 / pp;
            double b00 = d00 * ip, b11 = d11 * ip, b22 = d22 * ip;
            double b01 = m01 * ip, b02 = m02 * ip, b12 = m12 * ip;
            double detB = b00 * (b11 * b22 - b12 * b12)
                        - b01 * (b01 * b22 - b12 * b02)
                        + b02 * (b01 * b12 - b11 * b02);
            double rr = 0.5 * detB;
            rr = rr < -1.0 ? -1.0 : (rr > 1.0 ? 1.0 : rr);
            double phi = acos(rr) / 3.0;
            double lam = q3 + 2.0 * pp * cos(phi + 2.0943951023931953); // smallest eig
            double a00 = m00 - lam, a11 = m11 - lam, a22 = m22 - lam;
            double v0x = m01 * m12 - m02 * a11, v0y = m02 * m01 - a00 * m12, v0z = a00 * a11 - m01 * m01;
            double v1x = m01 * a22 - m02 * m12, v1y = m02 * m02 - a00 * a22, v1z = a00 * m12 - m01 * m02;
            double v2x = a11 * a22 - m12 * m12, v2y = m12 * m02 - m01 * a22, v2z = m01 * m12 - a11 * m02;
            double n0 = v0x * v0x + v0y * v0y + v0z * v0z;
            double n1 = v1x * v1x + v1y * v1y + v1z * v1z;
            double n2 = v2x * v2x + v2y * v2y + v2z * v2z;
            double bx = v0x, by = v0y, bz = v0z, bn = n0;
            if (n1 > bn) { bx = v1x; by = v1y; bz = v1z; bn = n1; }
            if (n2 > bn) { bx = v2x; by = v2y; bz = v2z; bn = n2; }
            if (bn > 1e-280) {
                double inv = 1.0 / sqrt(bn);
                nx = bx * inv; ny = by * inv; nz = bz * inv;
            }
        }
        double dq = -(qx * nx + qy * ny + qz * nz);
        if (dq < 0.0) { nx = -nx; ny = -ny; nz = -nz; }

        float* ob = out + (size_t)b * 6 * N_PTS;
        ob[3 * N_PTS + i] = (float)nx;
        ob[4 * N_PTS + i] = (float)ny;
        ob[5 * N_PTS + i] = (float)nz;
    }
}

// ---------------------------------------------------------------------------
extern "C" void kernel_launch(void* const* d_in, const int* in_sizes, int n_in,
                              void* d_out, int out_size, void* d_ws, size_t ws_size,
                              hipStream_t stream) {
    const float* x = (const float*)d_in[0];
    float* out = (float*)d_out;
    float4* pts = (float4*)d_ws;   // 32768 * 16 B = 512 KB scratch

    prep_kernel<<<dim3(32768 / 256), dim3(256), 0, stream>>>(x, pts, out);
    knn_normal_kernel<<<dim3(32768 / GROUPS), dim3(BLOCK), 0, stream>>>(pts, out);
}

// Round 6
// 348.223 us; speedup vs baseline: 7.6284x; 1.4933x over previous
//
#include <hip/hip_runtime.h>
#include <math.h>

#define N_PTS   8192
#define KNN     30
#define CAPG    112     // max stored candidates per group (lambda=55, +7.5 sigma)
#define STR     113     // LDS row stride (113*g % 32 distinct across 8 groups)
#define GROUPS  8       // queries per block (8 lanes per query)
#define BLOCK   64      // one wave per block
#define NBKT    512
#define ZLO     -4.0f
#define BSCALE  64.0f   // buckets per unit z: bucket = floor((z-ZLO)*BSCALE)

// ws layout: S float4[32768] @0 | O int[32768] @524288 | bstart int[4*513] @655360

// ---------------------------------------------------------------------------
// Per-batch counting sort by z (512 buckets) + out ch0..2 copy.
// One 256-thread block per batch. Emits sorted {x,y,z,xx_np}, orig idx, and
// bucket-start table. xx_np is the bitwise-numpy |p|^2 (no fma).
// ---------------------------------------------------------------------------
__global__ __launch_bounds__(256) void sort_kernel(const float* __restrict__ x,
                                                   float4* __restrict__ S,
                                                   int* __restrict__ O,
                                                   int* __restrict__ bstart,
                                                   float* __restrict__ out) {
    __shared__ int hist[NBKT];
    __shared__ int bst[NBKT + 1];
    __shared__ int cur[NBKT];
    const int b = blockIdx.x;
    const int t = threadIdx.x;
    const float* xb = x + (size_t)b * 3 * N_PTS;

    for (int k = t; k < NBKT; k += 256) hist[k] = 0;
    __syncthreads();
    for (int i = t; i < N_PTS; i += 256) {
        float pz = xb[2 * N_PTS + i];
        int bk = (int)floorf((pz - ZLO) * BSCALE);
        bk = bk < 0 ? 0 : (bk > NBKT - 1 ? NBKT - 1 : bk);
        atomicAdd(&hist[bk], 1);
    }
    __syncthreads();
    if (t < 64) {                          // wave-0 prefix scan over 512 buckets
        int base = t * 8;
        int loc[8], s = 0;
        #pragma unroll
        for (int k = 0; k < 8; ++k) { loc[k] = s; s += hist[base + k]; }
        int sum = s;
        #pragma unroll
        for (int off = 1; off < 64; off <<= 1) {
            int u = __shfl_up(sum, off);
            if (t >= off) sum += u;
        }
        int excl = sum - s;
        #pragma unroll
        for (int k = 0; k < 8; ++k) bst[base + k] = excl + loc[k];
        if (t == 63) bst[NBKT] = excl + s;
    }
    __syncthreads();
    for (int k = t; k < NBKT + 1; k += 256) bstart[b * (NBKT + 1) + k] = bst[k];
    for (int k = t; k < NBKT; k += 256) cur[k] = bst[k];
    __syncthreads();

    float4* Sb = S + ((size_t)b << 13);
    int*    Ob = O + ((size_t)b << 13);
    float*  ob = out + (size_t)b * 6 * N_PTS;
    for (int i = t; i < N_PTS; i += 256) {
        float px = xb[i], py = xb[N_PTS + i], pz = xb[2 * N_PTS + i];
        float xx = __fadd_rn(__fadd_rn(__fmul_rn(px, px), __fmul_rn(py, py)), __fmul_rn(pz, pz));
        int bk = (int)floorf((pz - ZLO) * BSCALE);
        bk = bk < 0 ? 0 : (bk > NBKT - 1 ? NBKT - 1 : bk);
        int dst = atomicAdd(&cur[bk], 1);
        Sb[dst] = make_float4(px, py, pz, xx);
        Ob[dst] = i;
        ob[i]             = px;            // out channels 0..2
        ob[N_PTS + i]     = py;
        ob[2 * N_PTS + i] = pz;
    }
}

// ---------------------------------------------------------------------------
// Main: one wave/block, 8 lanes/query, queries in sorted-z order. Scan only the
// z-slab |zj-zq| <= w (ball subset); ballot-compact hits; stable top-30 by lex
// (numpy-fp32 d, orig idx); fp64 cov + closed-form eigensolve.
// ---------------------------------------------------------------------------
__global__ __launch_bounds__(BLOCK) void knn_normal_kernel(const float4* __restrict__ S,
                                                           const int* __restrict__ O,
                                                           const int* __restrict__ bstart,
                                                           float* __restrict__ out) {
    __shared__ float lds_d[GROUPS * STR];
    __shared__ int   lds_i[GROUPS * STR];

    const int t   = threadIdx.x;          // 0..63
    const int l8  = t & 7;
    const int g   = t >> 3;
    const int gb  = t & ~7;
    const int qid = blockIdx.x * GROUPS + g;   // global sorted position
    const int b   = qid >> 13;
    const int pos = qid & (N_PTS - 1);
    const float4* __restrict__ P  = S + ((size_t)b << 13);
    const int*    __restrict__ Ob = O + ((size_t)b << 13);
    const int*    __restrict__ bs = bstart + b * (NBKT + 1);
    const float4 qp = P[pos];
    const int    oi = Ob[pos];            // original index of this query

    float* __restrict__ ldg = lds_d + g * STR;
    int*   __restrict__ lig = lds_i + g * STR;

    // ---- radius: solve lambda(r) = 55, lambda = Gaussian mass of ball(c,r)
    const float c = fmaxf(sqrtf(qp.w), 1e-3f);
    float rlo = 0.05f, rhi = 6.0f;
    for (int it = 0; it < 14; ++it) {
        float r = 0.5f * (rlo + rhi);
        float slo = fmaxf(c - r, 0.0f), shi = c + r;
        float h = (shi - slo) * 0.125f;
        float acc = 0.0f;
        #pragma unroll
        for (int k = 0; k <= 8; ++k) {
            float s  = slo + h * (float)k;
            float cs = c - s;
            float hh = fmaxf(fminf((r * r - cs * cs) * (0.5f / c), 2.0f * s), 0.0f);
            float f = __expf(-0.5f * s * s) * s * hh;
            float w = (k == 0 || k == 8) ? 1.0f : ((k & 1) ? 4.0f : 2.0f);
            acc = fmaf(w, f, acc);
        }
        float lam = 1089.3f * acc * h;    // 520.1 * 2*pi / 3
        if (lam < 55.0f) rlo = r; else rhi = r;
    }
    float rad0 = rhi * 1.02f;
    float r2  = rad0 * rad0;

    int  cnt = 0;
    bool active = true;

    for (;;) {
        if (active) {
            cnt = 0;
            float w = __fmaf_rn(sqrtf(r2), 1.002f, 1e-3f);   // slab guard band
            int blo = (int)floorf((qp.z - w - ZLO) * BSCALE);
            int bhi = (int)floorf((qp.z + w - ZLO) * BSCALE);
            blo = blo < 0 ? 0 : (blo > NBKT - 1 ? NBKT - 1 : blo);
            bhi = bhi < 0 ? 0 : (bhi > NBKT - 1 ? NBKT - 1 : bhi);
            int lo = bs[blo], hi = bs[bhi + 1];
            int smax = (hi - lo + 7) >> 3;     // uniform trip count per group
            for (int s = 0; s < smax; ++s) {
                int j  = lo + (s << 3) + l8;
                int jc = j < N_PTS - 1 ? j : N_PTS - 1;
                float4 p = P[jc];
                // bitwise numpy-fp32 pairwise distance
                float mm = __fmaf_rn(qp.z, p.z, __fmaf_rn(qp.y, p.y, __fmul_rn(qp.x, p.x)));
                float d  = __fsub_rn(__fadd_rn(qp.w, p.w), __fmul_rn(2.0f, mm));
                bool hit = (j < hi) && (d <= r2);
                unsigned long long m = __ballot(hit);
                unsigned sub = (unsigned)((m >> gb) & 0xFFull);
                if (hit) {
                    int slot = cnt + __popc(sub & ((1u << l8) - 1u));
                    if (slot < CAPG) { ldg[slot] = d; lig[slot] = jc; }
                }
                cnt += __popc(sub);            // group-uniform
            }
        }
        bool bad = active && (cnt < KNN || cnt > CAPG);
        if (__ballot(bad) == 0ULL) break;      // wave-uniform exit
        active = bad;
        if (active) r2 = (cnt < KNN) ? r2 * 1.6f : r2 * 0.82f;
    }

    // pack (sorted_pos<<16)|orig_idx so ranking ties break on ORIGINAL index
    for (int k = l8; k < cnt; k += 8) {
        int jc = lig[k];
        lig[k] = (jc << 16) | Ob[jc];
    }
    __syncthreads();                           // single wave: just a waitcnt

    // ---- stable top-30: lex (d, orig idx) rank within the group list ----
    const double qx = (double)qp.x, qy = (double)qp.y, qz = (double)qp.z;
    double sx = 0.0, sy = 0.0, sz = 0.0;
    double sxx = 0.0, sxy = 0.0, sxz = 0.0, syy = 0.0, syz = 0.0, szz = 0.0;

    for (int k = l8; k < cnt; k += 8) {
        float d   = ldg[k];
        int   pk  = lig[k];
        int   idx = pk & 0xFFFF;
        int rank = 0;
        for (int u = 0; u < cnt; ++u) {
            float d2 = ldg[u];
            int   i2 = lds_i[g * STR + u] & 0xFFFF;
            rank += (d2 < d || (d2 == d && i2 < idx)) ? 1 : 0;
        }
        if (rank < KNN) {                      // exactly 30 survivors per group
            float4 p = P[pk >> 16];
            double ax = (double)p.x - qx, ay = (double)p.y - qy, az = (double)p.z - qz;
            sx += ax; sy += ay; sz += az;
            sxx = fma(ax, ax, sxx); sxy = fma(ax, ay, sxy); sxz = fma(ax, az, sxz);
            syy = fma(ay, ay, syy); syz = fma(ay, az, syz); szz = fma(az, az, szz);
        }
    }

    // ---- reduce 9 fp64 sums across the 8-lane group ----
    #pragma unroll
    for (int off = 1; off < 8; off <<= 1) {
        sx  += __shfl_xor(sx,  off, 8); sy  += __shfl_xor(sy,  off, 8); sz  += __shfl_xor(sz,  off, 8);
        sxx += __shfl_xor(sxx, off, 8); sxy += __shfl_xor(sxy, off, 8); sxz += __shfl_xor(sxz, off, 8);
        syy += __shfl_xor(syy, off, 8); syz += __shfl_xor(syz, off, 8); szz += __shfl_xor(szz, off, 8);
    }

    if (l8 == 0) {
        const double kinv = 1.0 / (double)KNN;
        double m00 = sxx - sx * sx * kinv;
        double m11 = syy - sy * sy * kinv;
        double m22 = szz - sz * sz * kinv;
        double m01 = sxy - sx * sy * kinv;
        double m02 = sxz - sx * sz * kinv;
        double m12 = syz - sy * sz * kinv;

        double nx = 1.0, ny = 0.0, nz = 0.0;
        double q3 = (m00 + m11 + m22) / 3.0;
        double p1 = m01 * m01 + m02 * m02 + m12 * m12;
        double d00 = m00 - q3, d11 = m11 - q3, d22 = m22 - q3;
        double p2 = d00 * d00 + d11 * d11 + d22 * d22 + 2.0 * p1;
        if (p2 > 1e-280) {
            double pp = sqrt(p2 / 6.0);
            double ip = 1.0 / pp;
            double b00 = d00 * ip, b11 = d11 * ip, b22 = d22 * ip;
            double b01 = m01 * ip, b02 = m02 * ip, b12 = m12 * ip;
            double detB = b00 * (b11 * b22 - b12 * b12)
                        - b01 * (b01 * b22 - b12 * b02)
                        + b02 * (b01 * b12 - b11 * b02);
            double rr = 0.5 * detB;
            rr = rr < -1.0 ? -1.0 : (rr > 1.0 ? 1.0 : rr);
            double phi = acos(rr) / 3.0;
            double lam = q3 + 2.0 * pp * cos(phi + 2.0943951023931953); // smallest eig
            double a00 = m00 - lam, a11 = m11 - lam, a22 = m22 - lam;
            double v0x = m01 * m12 - m02 * a11, v0y = m02 * m01 - a00 * m12, v0z = a00 * a11 - m01 * m01;
            double v1x = m01 * a22 - m02 * m12, v1y = m02 * m02 - a00 * a22, v1z = a00 * m12 - m01 * m02;
            double v2x = a11 * a22 - m12 * m12, v2y = m12 * m02 - m01 * a22, v2z = m01 * m12 - a11 * m02;
            double n0 = v0x * v0x + v0y * v0y + v0z * v0z;
            double n1 = v1x * v1x + v1y * v1y + v1z * v1z;
            double n2 = v2x * v2x + v2y * v2y + v2z * v2z;
            double bx = v0x, by = v0y, bz = v0z, bn = n0;
            if (n1 > bn) { bx = v1x; by = v1y; bz = v1z; bn = n1; }
            if (n2 > bn) { bx = v2x; by = v2y; bz = v2z; bn = n2; }
            if (bn > 1e-280) {
                double inv = 1.0 / sqrt(bn);
                nx = bx * inv; ny = by * inv; nz = bz * inv;
            }
        }
        double dq = -(qx * nx + qy * ny + qz * nz);
        if (dq < 0.0) { nx = -nx; ny = -ny; nz = -nz; }

        float* ob = out + (size_t)b * 6 * N_PTS;
        ob[3 * N_PTS + oi] = (float)nx;
        ob[4 * N_PTS + oi] = (float)ny;
        ob[5 * N_PTS + oi] = (float)nz;
    }
}

// ---------------------------------------------------------------------------
extern "C" void kernel_launch(void* const* d_in, const int* in_sizes, int n_in,
                              void* d_out, int out_size, void* d_ws, size_t ws_size,
                              hipStream_t stream) {
    const float* x = (const float*)d_in[0];
    float* out = (float*)d_out;
    char* ws = (char*)d_ws;
    float4* S  = (float4*)(ws);              // 512 KB
    int*    O  = (int*)(ws + 524288);        // 128 KB
    int*    bs = (int*)(ws + 655360);        // 4*513*4 B

    sort_kernel<<<dim3(4), dim3(256), 0, stream>>>(x, S, O, bs, out);
    knn_normal_kernel<<<dim3(32768 / GROUPS), dim3(BLOCK), 0, stream>>>(S, O, bs, out);
}

// Round 7
// 212.919 us; speedup vs baseline: 12.4760x; 1.6355x over previous
//
#include <hip/hip_runtime.h>
#include <math.h>

#define N_PTS   8192
#define KNN     30
#define CAPG    104     // max stored candidates per group (lambda=48, +8 sigma)
#define STR     105     // LDS row stride in u64 (8 groups -> distinct bank pairs)
#define GROUPS  8       // queries per block
#define LPQ     16      // lanes per query
#define BLOCK   128     // 2 waves per block
#define NBKT    512
#define ZLO     -4.0f
#define BSCALE  64.0f   // bucket = floor((z-ZLO)*BSCALE)
#define LAMBDA  48.0f

// ws: S f4[32768]@0 | O i32[32768]@524288 | bstart@655360 (4*513*4)
//     hist@663568 (4*512*4) | cur@671760 (4*512*4) | R f32[32768]@679952

// ---------------------------------------------------------------------------
__global__ __launch_bounds__(256) void zero_kernel(int* __restrict__ hist) {
    hist[blockIdx.x * 256 + threadIdx.x] = 0;       // 8 blocks -> 2048 ints
}

__global__ __launch_bounds__(256) void hist_kernel(const float* __restrict__ x,
                                                   int* __restrict__ hist) {
    int gid = blockIdx.x * 256 + threadIdx.x;       // 128 blocks -> 32768
    int b = gid >> 13, i = gid & (N_PTS - 1);
    float pz = x[(size_t)b * 3 * N_PTS + 2 * N_PTS + i];
    int bk = (int)floorf((pz - ZLO) * BSCALE);
    bk = bk < 0 ? 0 : (bk > NBKT - 1 ? NBKT - 1 : bk);
    atomicAdd(&hist[b * NBKT + bk], 1);
}

// 1 block x 256: wave w scans batch w's 512 buckets (shfl inclusive scan)
__global__ __launch_bounds__(256) void scan_kernel(const int* __restrict__ hist,
                                                   int* __restrict__ bstart,
                                                   int* __restrict__ cur) {
    int t = threadIdx.x, b = t >> 6, lane = t & 63;
    const int* h = hist + b * NBKT;
    int base = lane * 8, loc[8], s = 0;
    #pragma unroll
    for (int k = 0; k < 8; ++k) { loc[k] = s; s += h[base + k]; }
    int sum = s;
    #pragma unroll
    for (int off = 1; off < 64; off <<= 1) {
        int u = __shfl_up(sum, off);
        if (lane >= off) sum += u;
    }
    int excl = sum - s;
    #pragma unroll
    for (int k = 0; k < 8; ++k) {
        int st = excl + loc[k];
        bstart[b * (NBKT + 1) + base + k] = st;
        cur[b * NBKT + base + k] = st;
    }
    if (lane == 63) bstart[b * (NBKT + 1) + NBKT] = excl + s;
}

// Scatter + xx_np + per-point radius solve (lambda=48) + out ch0..2 copy.
__global__ __launch_bounds__(256) void scatter_kernel(const float* __restrict__ x,
                                                      float4* __restrict__ S,
                                                      int* __restrict__ O,
                                                      float* __restrict__ R,
                                                      int* __restrict__ cur,
                                                      float* __restrict__ out) {
    int gid = blockIdx.x * 256 + threadIdx.x;       // 128 blocks -> 32768
    int b = gid >> 13, i = gid & (N_PTS - 1);
    const float* xb = x + (size_t)b * 3 * N_PTS;
    float px = xb[i], py = xb[N_PTS + i], pz = xb[2 * N_PTS + i];
    float xx = __fadd_rn(__fadd_rn(__fmul_rn(px, px), __fmul_rn(py, py)), __fmul_rn(pz, pz));
    int bk = (int)floorf((pz - ZLO) * BSCALE);
    bk = bk < 0 ? 0 : (bk > NBKT - 1 ? NBKT - 1 : bk);
    int dst = atomicAdd(&cur[b * NBKT + bk], 1);
    S[(b << 13) + dst] = make_float4(px, py, pz, xx);
    O[(b << 13) + dst] = i;

    // radius: solve lambda(r)=48, lambda = Gaussian mass of ball(c,r)
    const float c = fmaxf(sqrtf(xx), 1e-3f);
    float rlo = 0.05f, rhi = 6.0f;
    for (int it = 0; it < 14; ++it) {
        float r = 0.5f * (rlo + rhi);
        float slo = fmaxf(c - r, 0.0f), shi = c + r;
        float h = (shi - slo) * 0.125f;
        float acc = 0.0f;
        #pragma unroll
        for (int k = 0; k <= 8; ++k) {
            float s  = slo + h * (float)k;
            float cs = c - s;
            float hh = fmaxf(fminf((r * r - cs * cs) * (0.5f / c), 2.0f * s), 0.0f);
            float f = __expf(-0.5f * s * s) * s * hh;
            float w = (k == 0 || k == 8) ? 1.0f : ((k & 1) ? 4.0f : 2.0f);
            acc = fmaf(w, f, acc);
        }
        float lam = 1089.3f * acc * h;    // 520.1 * 2*pi / 3
        if (lam < LAMBDA) rlo = r; else rhi = r;
    }
    float rad = rhi * 1.02f;
    R[(b << 13) + dst] = rad * rad;

    float* ob = out + (size_t)b * 6 * N_PTS;
    ob[i]             = px;
    ob[N_PTS + i]     = py;
    ob[2 * N_PTS + i] = pz;
}

// ---------------------------------------------------------------------------
// Main: 16 lanes/query, 8 queries/block (2 waves). Slab scan, ballot-compact
// u64 keys (monotone f32 d | orig | jc) -> single-read rank; fp64 epilogue.
// ---------------------------------------------------------------------------
__global__ __launch_bounds__(BLOCK, 6) void knn_normal_kernel(const float4* __restrict__ S,
                                                              const int* __restrict__ O,
                                                              const int* __restrict__ bstart,
                                                              const float* __restrict__ R,
                                                              float* __restrict__ out) {
    __shared__ unsigned long long ldk[GROUPS * STR];

    const int t   = threadIdx.x;
    const int l16 = t & 15;
    const int g   = t >> 4;               // 0..7 (query within block)
    const int gsh = (t & 63) & ~15;       // ballot shift within this wave
    const int qid = blockIdx.x * GROUPS + g;
    const int b   = qid >> 13;
    const int pos = qid & (N_PTS - 1);
    const float4* __restrict__ P  = S + ((size_t)b << 13);
    const int*    __restrict__ Ob = O + ((size_t)b << 13);
    const int*    __restrict__ bs = bstart + b * (NBKT + 1);
    const float4 qp = P[pos];
    const int    oi = Ob[pos];

    unsigned long long* __restrict__ ldg = ldk + g * STR;

    float r2 = R[((size_t)b << 13) + pos];
    int  cnt = 0;
    bool active = true;

    for (;;) {
        if (active) {
            cnt = 0;
            float w = __fmaf_rn(sqrtf(r2), 1.002f, 1e-3f);   // slab guard band
            int blo = (int)floorf((qp.z - w - ZLO) * BSCALE);
            int bhi = (int)floorf((qp.z + w - ZLO) * BSCALE);
            blo = blo < 0 ? 0 : (blo > NBKT - 1 ? NBKT - 1 : blo);
            bhi = bhi < 0 ? 0 : (bhi > NBKT - 1 ? NBKT - 1 : bhi);
            int lo = bs[blo], hi = bs[bhi + 1];
            int smax = (hi - lo + 15) >> 4;       // group-uniform trip count
            for (int s = 0; s < smax; ++s) {
                int j  = lo + (s << 4) + l16;
                int jc = j < N_PTS ? j : N_PTS - 1;
                float4 p = P[jc];
                // bitwise numpy-fp32 pairwise distance
                float mm = __fmaf_rn(qp.z, p.z, __fmaf_rn(qp.y, p.y, __fmul_rn(qp.x, p.x)));
                float d  = __fsub_rn(__fadd_rn(qp.w, p.w), __fmul_rn(2.0f, mm));
                bool hit = (j < hi) && (d <= r2);
                unsigned long long m = __ballot(hit);
                unsigned sub = (unsigned)((m >> gsh) & 0xFFFFull);
                if (hit) {
                    int slot = cnt + __popc(sub & ((1u << l16) - 1u));
                    if (slot < CAPG) {
                        unsigned u = __float_as_uint(d);
                        u = (u & 0x80000000u) ? ~u : (u | 0x80000000u);  // monotone
                        ldg[slot] = ((unsigned long long)u << 28) | (unsigned long long)jc;
                    }
                }
                cnt += __popc(sub);               // group-uniform
            }
        }
        bool bad = active && (cnt < KNN || cnt > CAPG);
        if (__ballot(bad) == 0ULL) break;         // wave-uniform exit
        active = bad;
        if (active) r2 = (cnt < KNN) ? r2 * 1.6f : r2 * 0.82f;
    }

    // fill orig-idx field (bits 14..27) so u64 order == lex (d, orig idx)
    for (int k = l16; k < cnt; k += 16) {
        unsigned long long key = ldg[k];
        int jc = (int)(key & 0x3FFFull);
        ldg[k] = (key & ~0x0FFFFFFFull) | ((unsigned long long)Ob[jc] << 14) | (unsigned long long)jc;
    }
    __syncthreads();

    // ---- stable top-30: rank by u64 key (keys unique) ----
    const double qx = (double)qp.x, qy = (double)qp.y, qz = (double)qp.z;
    double sx = 0.0, sy = 0.0, sz = 0.0;
    double sxx = 0.0, sxy = 0.0, sxz = 0.0, syy = 0.0, syz = 0.0, szz = 0.0;

    for (int k = l16; k < cnt; k += 16) {
        unsigned long long key = ldg[k];
        int rank = 0;
        for (int u = 0; u < cnt; ++u) rank += (ldg[u] < key) ? 1 : 0;
        if (rank < KNN) {                         // exactly 30 survivors
            float4 p = P[(int)(key & 0x3FFFull)];
            double ax = (double)p.x - qx, ay = (double)p.y - qy, az = (double)p.z - qz;
            sx += ax; sy += ay; sz += az;
            sxx = fma(ax, ax, sxx); sxy = fma(ax, ay, sxy); sxz = fma(ax, az, sxz);
            syy = fma(ay, ay, syy); syz = fma(ay, az, syz); szz = fma(az, az, szz);
        }
    }

    #pragma unroll
    for (int off = 1; off < 16; off <<= 1) {
        sx  += __shfl_xor(sx,  off, 16); sy  += __shfl_xor(sy,  off, 16); sz  += __shfl_xor(sz,  off, 16);
        sxx += __shfl_xor(sxx, off, 16); sxy += __shfl_xor(sxy, off, 16); sxz += __shfl_xor(sxz, off, 16);
        syy += __shfl_xor(syy, off, 16); syz += __shfl_xor(syz, off, 16); szz += __shfl_xor(szz, off, 16);
    }

    if (l16 == 0) {
        const double kinv = 1.0 / (double)KNN;
        double m00 = sxx - sx * sx * kinv;
        double m11 = syy - sy * sy * kinv;
        double m22 = szz - sz * sz * kinv;
        double m01 = sxy - sx * sy * kinv;
        double m02 = sxz - sx * sz * kinv;
        double m12 = syz - sy * sz * kinv;

        double nx = 1.0, ny = 0.0, nz = 0.0;
        double q3 = (m00 + m11 + m22) / 3.0;
        double p1 = m01 * m01 + m02 * m02 + m12 * m12;
        double d00 = m00 - q3, d11 = m11 - q3, d22 = m22 - q3;
        double p2 = d00 * d00 + d11 * d11 + d22 * d22 + 2.0 * p1;
        if (p2 > 1e-280) {
            double pp = sqrt(p2 / 6.0);
            double ip = 1.0 / pp;
            double b00 = d00 * ip, b11 = d11 * ip, b22 = d22 * ip;
            double b01 = m01 * ip, b02 = m02 * ip, b12 = m12 * ip;
            double detB = b00 * (b11 * b22 - b12 * b12)
                        - b01 * (b01 * b22 - b12 * b02)
                        + b02 * (b01 * b12 - b11 * b02);
            double rr = 0.5 * detB;
            rr = rr < -1.0 ? -1.0 : (rr > 1.0 ? 1.0 : rr);
            double phi = acos(rr) / 3.0;
            double lam = q3 + 2.0 * pp * cos(phi + 2.0943951023931953); // smallest eig
            double a00 = m00 - lam, a11 = m11 - lam, a22 = m22 - lam;
            double v0x = m01 * m12 - m02 * a11, v0y = m02 * m01 - a00 * m12, v0z = a00 * a11 - m01 * m01;
            double v1x = m01 * a22 - m02 * m12, v1y = m02 * m02 - a00 * a22, v1z = a00 * m12 - m01 * m02;
            double v2x = a11 * a22 - m12 * m12, v2y = m12 * m02 - m01 * a22, v2z = m01 * m12 - a11 * m02;
            double n0 = v0x * v0x + v0y * v0y + v0z * v0z;
            double n1 = v1x * v1x + v1y * v1y + v1z * v1z;
            double n2 = v2x * v2x + v2y * v2y + v2z * v2z;
            double bx = v0x, by = v0y, bz = v0z, bn = n0;
            if (n1 > bn) { bx = v1x; by = v1y; bz = v1z; bn = n1; }
            if (n2 > bn) { bx = v2x; by = v2y; bz = v2z; bn = n2; }
            if (bn > 1e-280) {
                double inv = 1.0 / sqrt(bn);
                nx = bx * inv; ny = by * inv; nz = bz * inv;
            }
        }
        double dq = -(qx * nx + qy * ny + qz * nz);
        if (dq < 0.0) { nx = -nx; ny = -ny; nz = -nz; }

        float* ob = out + (size_t)b * 6 * N_PTS;
        ob[3 * N_PTS + oi] = (float)nx;
        ob[4 * N_PTS + oi] = (float)ny;
        ob[5 * N_PTS + oi] = (float)nz;
    }
}

// ---------------------------------------------------------------------------
extern "C" void kernel_launch(void* const* d_in, const int* in_sizes, int n_in,
                              void* d_out, int out_size, void* d_ws, size_t ws_size,
                              hipStream_t stream) {
    const float* x = (const float*)d_in[0];
    float* out = (float*)d_out;
    char* ws = (char*)d_ws;
    float4* S    = (float4*)(ws);                 // 512 KB
    int*    O    = (int*)(ws + 524288);           // 128 KB
    int*    bsta = (int*)(ws + 655360);           // 8208 B
    int*    hist = (int*)(ws + 663568);           // 8192 B
    int*    cur  = (int*)(ws + 671760);           // 8192 B
    float*  R    = (float*)(ws + 679952);         // 128 KB

    zero_kernel<<<dim3(8), dim3(256), 0, stream>>>(hist);
    hist_kernel<<<dim3(128), dim3(256), 0, stream>>>(x, hist);
    scan_kernel<<<dim3(1), dim3(256), 0, stream>>>(hist, bsta, cur);
    scatter_kernel<<<dim3(128), dim3(256), 0, stream>>>(x, S, O, R, cur, out);
    knn_normal_kernel<<<dim3(32768 / GROUPS), dim3(BLOCK), 0, stream>>>(S, O, bsta, R, out);
}

// Round 8
// 191.510 us; speedup vs baseline: 13.8707x; 1.1118x over previous
//
#include <hip/hip_runtime.h>
#include <math.h>

#define N_PTS   8192
#define KNN     30
#define CAPG    104     // max stored candidates per group (lambda=48, +8 sigma)
#define STR     105     // LDS row stride in u64
#define GROUPS  8       // queries per block
#define LPQ     16      // lanes per query
#define BLOCK   128     // 2 waves per block
#define NZ      64
#define NY      64
#define NBKT    (NZ * NY)
#define CLO     -4.0f
#define CSC     8.0f    // buckets per unit: bucket = floor((c - CLO) * CSC)
#define LAMBDA  48.0f

// ws: S f4[32768]@0 | O i32[32768]@524288 | bstart@655360 (4*4097*4)
//     hist@720912 (4*4096*4) | cur@786448 (4*4096*4) | R f32[32768]@851984

__device__ __forceinline__ int clampi(int v, int lo, int hi) {
    return v < lo ? lo : (v > hi ? hi : v);
}
__device__ __forceinline__ int bucket_of(float pz, float py) {
    int zb = clampi((int)floorf((pz - CLO) * CSC), 0, NZ - 1);
    int yb = clampi((int)floorf((py - CLO) * CSC), 0, NY - 1);
    return (zb << 6) | yb;
}

// ---------------------------------------------------------------------------
__global__ __launch_bounds__(256) void hist_kernel(const float* __restrict__ x,
                                                   int* __restrict__ hist) {
    int gid = blockIdx.x * 256 + threadIdx.x;       // 128 blocks -> 32768
    int b = gid >> 13, i = gid & (N_PTS - 1);
    const float* xb = x + (size_t)b * 3 * N_PTS;
    float py = xb[N_PTS + i], pz = xb[2 * N_PTS + i];
    atomicAdd(&hist[b * NBKT + bucket_of(pz, py)], 1);
}

// 1 block x 256: wave w scans batch w's 4096 buckets (2-pass + shfl scan)
__global__ __launch_bounds__(256) void scan_kernel(const int* __restrict__ hist,
                                                   int* __restrict__ bstart,
                                                   int* __restrict__ cur) {
    int t = threadIdx.x, b = t >> 6, lane = t & 63;
    const int* h = hist + b * NBKT;
    int base = lane * 64;
    int s = 0;
    for (int k = 0; k < 64; ++k) s += h[base + k];
    int sum = s;
    #pragma unroll
    for (int off = 1; off < 64; off <<= 1) {
        int u = __shfl_up(sum, off);
        if (lane >= off) sum += u;
    }
    int run = sum - s;                              // exclusive prefix
    for (int k = 0; k < 64; ++k) {
        bstart[b * (NBKT + 1) + base + k] = run;
        cur[b * NBKT + base + k] = run;
        run += h[base + k];
    }
    if (lane == 63) bstart[b * (NBKT + 1) + NBKT] = run;
}

// Scatter + xx_np + per-point radius solve (lambda=48) + out ch0..2 copy.
__global__ __launch_bounds__(256) void scatter_kernel(const float* __restrict__ x,
                                                      float4* __restrict__ S,
                                                      int* __restrict__ O,
                                                      float* __restrict__ R,
                                                      int* __restrict__ cur,
                                                      float* __restrict__ out) {
    int gid = blockIdx.x * 256 + threadIdx.x;       // 128 blocks -> 32768
    int b = gid >> 13, i = gid & (N_PTS - 1);
    const float* xb = x + (size_t)b * 3 * N_PTS;
    float px = xb[i], py = xb[N_PTS + i], pz = xb[2 * N_PTS + i];
    float xx = __fadd_rn(__fadd_rn(__fmul_rn(px, px), __fmul_rn(py, py)), __fmul_rn(pz, pz));
    int dst = atomicAdd(&cur[b * NBKT + bucket_of(pz, py)], 1);
    S[(b << 13) + dst] = make_float4(px, py, pz, xx);
    O[(b << 13) + dst] = i;

    // radius: solve lambda(r)=48, lambda = Gaussian mass of ball(c,r)
    const float c = fmaxf(sqrtf(xx), 1e-3f);
    float rlo = 0.05f, rhi = 6.0f;
    for (int it = 0; it < 14; ++it) {
        float r = 0.5f * (rlo + rhi);
        float slo = fmaxf(c - r, 0.0f), shi = c + r;
        float h = (shi - slo) * 0.125f;
        float acc = 0.0f;
        #pragma unroll
        for (int k = 0; k <= 8; ++k) {
            float s  = slo + h * (float)k;
            float cs = c - s;
            float hh = fmaxf(fminf((r * r - cs * cs) * (0.5f / c), 2.0f * s), 0.0f);
            float f = __expf(-0.5f * s * s) * s * hh;
            float w = (k == 0 || k == 8) ? 1.0f : ((k & 1) ? 4.0f : 2.0f);
            acc = fmaf(w, f, acc);
        }
        float lam = 1089.3f * acc * h;    // 520.1 * 2*pi / 3
        if (lam < LAMBDA) rlo = r; else rhi = r;
    }
    float rad = rhi * 1.02f;
    R[(b << 13) + dst] = rad * rad;

    float* ob = out + (size_t)b * 6 * N_PTS;
    ob[i]             = px;
    ob[N_PTS + i]     = py;
    ob[2 * N_PTS + i] = pz;
}

// ---------------------------------------------------------------------------
// Main: 16 lanes/query, 8 queries/block. (z,y)-window segment scan over the
// 2-D-bucketed array; ballot-compact u64 keys; rank select; fp64 epilogue.
// ---------------------------------------------------------------------------
__global__ __launch_bounds__(BLOCK, 6) void knn_normal_kernel(const float4* __restrict__ S,
                                                              const int* __restrict__ O,
                                                              const int* __restrict__ bstart,
                                                              const float* __restrict__ R,
                                                              float* __restrict__ out) {
    __shared__ unsigned long long ldk[GROUPS * STR];

    const int t    = threadIdx.x;
    const int l16  = t & 15;
    const int g    = t >> 4;
    const int gsh  = (t & 63) & ~15;
    const int qblk = (blockIdx.x * 1031) & 4095;   // bijective swizzle: flatten tail
    const int qid  = qblk * GROUPS + g;
    const int b    = qid >> 13;
    const int pos  = qid & (N_PTS - 1);
    const float4* __restrict__ P  = S + ((size_t)b << 13);
    const int*    __restrict__ Ob = O + ((size_t)b << 13);
    const int*    __restrict__ bs = bstart + b * (NBKT + 1);
    const float4 qp = P[pos];
    const int    oi = Ob[pos];

    unsigned long long* __restrict__ ldg = ldk + g * STR;

    float r2 = R[((size_t)b << 13) + pos];
    int  cnt = 0;
    bool active = true;

    for (;;) {
        if (active) {
            cnt = 0;
            float w = __fmaf_rn(sqrtf(r2), 1.002f, 1e-3f);   // guard band
            int zlo = clampi((int)floorf((qp.z - w - CLO) * CSC), 0, NZ - 1);
            int zhi = clampi((int)floorf((qp.z + w - CLO) * CSC), 0, NZ - 1);
            int ylo = clampi((int)floorf((qp.y - w - CLO) * CSC), 0, NY - 1);
            int yhi = clampi((int)floorf((qp.y + w - CLO) * CSC), 0, NY - 1);
            for (int zb = zlo; zb <= zhi; ++zb) {
                int lo = bs[(zb << 6) + ylo];
                int hi = bs[(zb << 6) + yhi + 1];
                int smax = (hi - lo + 15) >> 4;   // group-uniform
                #pragma unroll 2
                for (int s = 0; s < smax; ++s) {
                    int j  = lo + (s << 4) + l16;
                    int jc = j < hi ? j : hi - 1;
                    float4 p = P[jc];
                    // bitwise numpy-fp32 pairwise distance
                    float mm = __fmaf_rn(qp.z, p.z, __fmaf_rn(qp.y, p.y, __fmul_rn(qp.x, p.x)));
                    float d  = __fsub_rn(__fadd_rn(qp.w, p.w), __fmul_rn(2.0f, mm));
                    bool hit = (j < hi) && (d <= r2);
                    unsigned long long m = __ballot(hit);
                    unsigned sub = (unsigned)((m >> gsh) & 0xFFFFull);
                    if (hit) {
                        int slot = cnt + __popc(sub & ((1u << l16) - 1u));
                        if (slot < CAPG) {
                            unsigned u = __float_as_uint(d);
                            u = (u & 0x80000000u) ? ~u : (u | 0x80000000u);  // monotone
                            ldg[slot] = ((unsigned long long)u << 28) | (unsigned long long)jc;
                        }
                    }
                    cnt += __popc(sub);           // group-uniform
                }
            }
        }
        bool bad = active && (cnt < KNN || cnt > CAPG);
        if (__ballot(bad) == 0ULL) break;         // wave-uniform exit
        active = bad;
        if (active) r2 = (cnt < KNN) ? r2 * 1.6f : r2 * 0.82f;
    }

    // fill orig-idx field (bits 14..27) so u64 order == lex (d, orig idx)
    for (int k = l16; k < cnt; k += 16) {
        unsigned long long key = ldg[k];
        int jc = (int)(key & 0x3FFFull);
        ldg[k] = (key & ~0x0FFFFFFFull) | ((unsigned long long)Ob[jc] << 14) | (unsigned long long)jc;
    }
    __syncthreads();

    // ---- stable top-30: rank by u64 key (keys unique) ----
    const double qx = (double)qp.x, qy = (double)qp.y, qz = (double)qp.z;
    double sx = 0.0, sy = 0.0, sz = 0.0;
    double sxx = 0.0, sxy = 0.0, sxz = 0.0, syy = 0.0, syz = 0.0, szz = 0.0;

    for (int k = l16; k < cnt; k += 16) {
        unsigned long long key = ldg[k];
        int rank = 0;
        for (int u = 0; u < cnt; ++u) rank += (ldg[u] < key) ? 1 : 0;
        if (rank < KNN) {                         // exactly 30 survivors
            float4 p = P[(int)(key & 0x3FFFull)];
            double ax = (double)p.x - qx, ay = (double)p.y - qy, az = (double)p.z - qz;
            sx += ax; sy += ay; sz += az;
            sxx = fma(ax, ax, sxx); sxy = fma(ax, ay, sxy); sxz = fma(ax, az, sxz);
            syy = fma(ay, ay, syy); syz = fma(ay, az, syz); szz = fma(az, az, szz);
        }
    }

    #pragma unroll
    for (int off = 1; off < 16; off <<= 1) {
        sx  += __shfl_xor(sx,  off, 16); sy  += __shfl_xor(sy,  off, 16); sz  += __shfl_xor(sz,  off, 16);
        sxx += __shfl_xor(sxx, off, 16); sxy += __shfl_xor(sxy, off, 16); sxz += __shfl_xor(sxz, off, 16);
        syy += __shfl_xor(syy, off, 16); syz += __shfl_xor(syz, off, 16); szz += __shfl_xor(szz, off, 16);
    }

    if (l16 == 0) {
        const double kinv = 1.0 / (double)KNN;
        double m00 = sxx - sx * sx * kinv;
        double m11 = syy - sy * sy * kinv;
        double m22 = szz - sz * sz * kinv;
        double m01 = sxy - sx * sy * kinv;
        double m02 = sxz - sx * sz * kinv;
        double m12 = syz - sy * sz * kinv;

        double nx = 1.0, ny = 0.0, nz = 0.0;
        double q3 = (m00 + m11 + m22) / 3.0;
        double p1 = m01 * m01 + m02 * m02 + m12 * m12;
        double d00 = m00 - q3, d11 = m11 - q3, d22 = m22 - q3;
        double p2 = d00 * d00 + d11 * d11 + d22 * d22 + 2.0 * p1;
        if (p2 > 1e-280) {
            double pp = sqrt(p2 / 6.0);
            double ip = 1.0 / pp;
            double b00 = d00 * ip, b11 = d11 * ip, b22 = d22 * ip;
            double b01 = m01 * ip, b02 = m02 * ip, b12 = m12 * ip;
            double detB = b00 * (b11 * b22 - b12 * b12)
                        - b01 * (b01 * b22 - b12 * b02)
                        + b02 * (b01 * b12 - b11 * b02);
            double rr = 0.5 * detB;
            rr = rr < -1.0 ? -1.0 : (rr > 1.0 ? 1.0 : rr);
            double phi = acos(rr) / 3.0;
            double lam = q3 + 2.0 * pp * cos(phi + 2.0943951023931953); // smallest eig
            double a00 = m00 - lam, a11 = m11 - lam, a22 = m22 - lam;
            double v0x = m01 * m12 - m02 * a11, v0y = m02 * m01 - a00 * m12, v0z = a00 * a11 - m01 * m01;
            double v1x = m01 * a22 - m02 * m12, v1y = m02 * m02 - a00 * a22, v1z = a00 * m12 - m01 * m02;
            double v2x = a11 * a22 - m12 * m12, v2y = m12 * m02 - m01 * a22, v2z = m01 * m12 - a11 * m02;
            double n0 = v0x * v0x + v0y * v0y + v0z * v0z;
            double n1 = v1x * v1x + v1y * v1y + v1z * v1z;
            double n2 = v2x * v2x + v2y * v2y + v2z * v2z;
            double bx = v0x, by = v0y, bz = v0z, bn = n0;
            if (n1 > bn) { bx = v1x; by = v1y; bz = v1z; bn = n1; }
            if (n2 > bn) { bx = v2x; by = v2y; bz = v2z; bn = n2; }
            if (bn > 1e-280) {
                double inv = 1.0 / sqrt(bn);
                nx = bx * inv; ny = by * inv; nz = bz * inv;
            }
        }
        double dq = -(qx * nx + qy * ny + qz * nz);
        if (dq < 0.0) { nx = -nx; ny = -ny; nz = -nz; }

        float* ob = out + (size_t)b * 6 * N_PTS;
        ob[3 * N_PTS + oi] = (float)nx;
        ob[4 * N_PTS + oi] = (float)ny;
        ob[5 * N_PTS + oi] = (float)nz;
    }
}

// ---------------------------------------------------------------------------
extern "C" void kernel_launch(void* const* d_in, const int* in_sizes, int n_in,
                              void* d_out, int out_size, void* d_ws, size_t ws_size,
                              hipStream_t stream) {
    const float* x = (const float*)d_in[0];
    float* out = (float*)d_out;
    char* ws = (char*)d_ws;
    float4* S    = (float4*)(ws);                 // 512 KB
    int*    O    = (int*)(ws + 524288);           // 128 KB
    int*    bsta = (int*)(ws + 655360);           // 4*4097*4 = 65552 B
    int*    hist = (int*)(ws + 720912);           // 65536 B
    int*    cur  = (int*)(ws + 786448);           // 65536 B
    float*  R    = (float*)(ws + 851984);         // 128 KB

    hipMemsetAsync(hist, 0, 4 * NBKT * sizeof(int), stream);
    hist_kernel<<<dim3(128), dim3(256), 0, stream>>>(x, hist);
    scan_kernel<<<dim3(1), dim3(256), 0, stream>>>(hist, bsta, cur);
    scatter_kernel<<<dim3(128), dim3(256), 0, stream>>>(x, S, O, R, cur, out);
    knn_normal_kernel<<<dim3(32768 / GROUPS), dim3(BLOCK), 0, stream>>>(S, O, bsta, R, out);
}

// Round 9
// 164.462 us; speedup vs baseline: 16.1518x; 1.1645x over previous
//
#include <hip/hip_runtime.h>
#include <math.h>

#define N_PTS   8192
#define KNN     30
#define CAPG    104     // max stored candidates per group (lambda=48, +8 sigma)
#define STR     105     // LDS row stride in u64
#define GROUPS  8       // queries per block
#define BLOCK   128     // 2 waves per block
#define NZ      64
#define NY      64
#define NBKT    (NZ * NY)
#define CLO     -4.0f
#define CSC     8.0f    // buckets per unit: bucket = floor((c - CLO) * CSC)
#define LAMBDA  48.0f

// ws: S f4[32768]@0 | O i32[32768]@524288 | bstart i32[4*4097]@655360

__device__ __forceinline__ int clampi(int v, int lo, int hi) {
    return v < lo ? lo : (v > hi ? hi : v);
}
__device__ __forceinline__ int bucket_of(float pz, float py) {
    int zb = clampi((int)floorf((pz - CLO) * CSC), 0, NZ - 1);
    int yb = clampi((int)floorf((py - CLO) * CSC), 0, NY - 1);
    return (zb << 6) | yb;
}

// ---------------------------------------------------------------------------
// Fused prep: one block per batch (1024 threads). LDS hist -> in-block scan ->
// LDS-atomic counting-sort scatter. Also copies x into out ch0..2.
// ---------------------------------------------------------------------------
__global__ __launch_bounds__(1024) void prep_kernel(const float* __restrict__ x,
                                                    float4* __restrict__ S,
                                                    int* __restrict__ O,
                                                    int* __restrict__ bstart,
                                                    float* __restrict__ out) {
    __shared__ int hist[NBKT];    // 16 KB
    __shared__ int cur[NBKT];     // 16 KB (bucket cursors)
    __shared__ int wsum[16];

    const int b = blockIdx.x;
    const int t = threadIdx.x;
    const int wid = t >> 6, lane = t & 63;
    const float* xb = x + (size_t)b * 3 * N_PTS;
    float* ob = out + (size_t)b * 6 * N_PTS;

    for (int k = t; k < NBKT; k += 1024) hist[k] = 0;
    __syncthreads();

    float px[8], py[8], pz[8];
    int   bk[8];
    #pragma unroll
    for (int u = 0; u < 8; ++u) {
        int i = (u << 10) + t;
        px[u] = xb[i]; py[u] = xb[N_PTS + i]; pz[u] = xb[2 * N_PTS + i];
        bk[u] = bucket_of(pz[u], py[u]);
        atomicAdd(&hist[bk[u]], 1);
        ob[i]             = px[u];
        ob[N_PTS + i]     = py[u];
        ob[2 * N_PTS + i] = pz[u];
    }
    __syncthreads();

    // block scan: thread t owns buckets 4t..4t+3
    int l0 = hist[4 * t], l1 = hist[4 * t + 1], l2 = hist[4 * t + 2], l3 = hist[4 * t + 3];
    int s = l0 + l1 + l2 + l3;
    int sum = s;
    #pragma unroll
    for (int off = 1; off < 64; off <<= 1) {
        int v = __shfl_up(sum, off);
        if (lane >= off) sum += v;
    }
    if (lane == 63) wsum[wid] = sum;
    __syncthreads();
    if (t == 0) {
        int run = 0;
        #pragma unroll
        for (int k = 0; k < 16; ++k) { int v = wsum[k]; wsum[k] = run; run += v; }
    }
    __syncthreads();
    int base = wsum[wid] + (sum - s);     // exclusive prefix for this thread
    int b0 = base, b1 = base + l0, b2 = b1 + l1, b3 = b2 + l2;
    cur[4 * t] = b0; cur[4 * t + 1] = b1; cur[4 * t + 2] = b2; cur[4 * t + 3] = b3;
    int* bsb = bstart + b * (NBKT + 1);
    bsb[4 * t] = b0; bsb[4 * t + 1] = b1; bsb[4 * t + 2] = b2; bsb[4 * t + 3] = b3;
    if (t == 1023) bsb[NBKT] = N_PTS;
    __syncthreads();

    // scatter (xx_np = bitwise-numpy |p|^2, no fma)
    float4* Sb = S + ((size_t)b << 13);
    int*    Ob = O + ((size_t)b << 13);
    #pragma unroll
    for (int u = 0; u < 8; ++u) {
        int dst = atomicAdd(&cur[bk[u]], 1);
        float xx = __fadd_rn(__fadd_rn(__fmul_rn(px[u], px[u]), __fmul_rn(py[u], py[u])),
                             __fmul_rn(pz[u], pz[u]));
        Sb[dst] = make_float4(px[u], py[u], pz[u], xx);
        Ob[dst] = (u << 10) + t;
    }
}

// ---------------------------------------------------------------------------
// Main: 16 lanes/query, 8 queries/block. Lane-parallel radius solve; 2x-unrolled
// (z,y)-window segment scan; ballot-compact u64 keys; rank select; fp64 epilogue.
// ---------------------------------------------------------------------------
__global__ __launch_bounds__(BLOCK, 6) void knn_normal_kernel(const float4* __restrict__ S,
                                                              const int* __restrict__ O,
                                                              const int* __restrict__ bstart,
                                                              float* __restrict__ out) {
    __shared__ unsigned long long ldk[GROUPS * STR];

    const int t    = threadIdx.x;
    const int l16  = t & 15;
    const int g    = t >> 4;
    const int gsh  = (t & 63) & ~15;
    const int qblk = (blockIdx.x * 1031) & 4095;   // bijective swizzle: flatten tail
    const int qid  = qblk * GROUPS + g;
    const int b    = qid >> 13;
    const int pos  = qid & (N_PTS - 1);
    const float4* __restrict__ P  = S + ((size_t)b << 13);
    const int*    __restrict__ Ob = O + ((size_t)b << 13);
    const int*    __restrict__ bs = bstart + b * (NBKT + 1);
    const float4 qp = P[pos];
    const int    oi = Ob[pos];

    unsigned long long* __restrict__ ldg = ldk + g * STR;

    // ---- radius: solve lambda(r)=48 (Gaussian ball mass), lane-parallel Simpson-9
    const float c = fmaxf(sqrtf(qp.w), 1e-3f);
    float rlo = 0.05f, rhi = 6.0f;
    for (int it = 0; it < 14; ++it) {
        float r = 0.5f * (rlo + rhi);
        float slo = fmaxf(c - r, 0.0f);
        float h = (c + r - slo) * 0.125f;
        float f = 0.0f;
        if (l16 <= 8) {
            float sq = slo + h * (float)l16;
            float cs = c - sq;
            float hh = fmaxf(fminf((r * r - cs * cs) * (0.5f / c), 2.0f * sq), 0.0f);
            float w = (l16 == 0 || l16 == 8) ? 1.0f : ((l16 & 1) ? 4.0f : 2.0f);
            f = w * __expf(-0.5f * sq * sq) * sq * hh;
        }
        f += __shfl_xor(f, 1, 16); f += __shfl_xor(f, 2, 16);
        f += __shfl_xor(f, 4, 16); f += __shfl_xor(f, 8, 16);
        float lam = 1089.3f * f * h;       // 520.1 * 2*pi / 3
        if (lam < LAMBDA) rlo = r; else rhi = r;
    }
    float rad = rhi * 1.02f;
    float r2  = rad * rad;

    int  cnt = 0;
    bool active = true;

    for (;;) {
        if (active) {
            cnt = 0;
            float w = __fmaf_rn(sqrtf(r2), 1.002f, 1e-3f);   // guard band
            int zlo = clampi((int)floorf((qp.z - w - CLO) * CSC), 0, NZ - 1);
            int zhi = clampi((int)floorf((qp.z + w - CLO) * CSC), 0, NZ - 1);
            int ylo = clampi((int)floorf((qp.y - w - CLO) * CSC), 0, NY - 1);
            int yhi = clampi((int)floorf((qp.y + w - CLO) * CSC), 0, NY - 1);
            for (int zb = zlo; zb <= zhi; ++zb) {
                int lo = bs[(zb << 6) + ylo];
                int hi = bs[(zb << 6) + yhi + 1];
                int smax = (hi - lo + 31) >> 5;   // group-uniform, 32 cand/iter
                for (int s = 0; s < smax; ++s) {
                    int j1  = lo + (s << 5) + l16;
                    int j2  = j1 + 16;
                    int jc1 = j1 < hi ? j1 : hi - 1;
                    int jc2 = j2 < hi ? j2 : hi - 1;
                    float4 p1 = P[jc1];
                    float4 p2 = P[jc2];
                    float mm1 = __fmaf_rn(qp.z, p1.z, __fmaf_rn(qp.y, p1.y, __fmul_rn(qp.x, p1.x)));
                    float d1  = __fsub_rn(__fadd_rn(qp.w, p1.w), __fmul_rn(2.0f, mm1));
                    float mm2 = __fmaf_rn(qp.z, p2.z, __fmaf_rn(qp.y, p2.y, __fmul_rn(qp.x, p2.x)));
                    float d2  = __fsub_rn(__fadd_rn(qp.w, p2.w), __fmul_rn(2.0f, mm2));
                    bool hit1 = (j1 < hi) && (d1 <= r2);
                    bool hit2 = (j2 < hi) && (d2 <= r2);
                    unsigned long long m1 = __ballot(hit1);
                    unsigned sub1 = (unsigned)((m1 >> gsh) & 0xFFFFull);
                    if (hit1) {
                        int slot = cnt + __popc(sub1 & ((1u << l16) - 1u));
                        if (slot < CAPG) {
                            unsigned u = __float_as_uint(d1);
                            u = (u & 0x80000000u) ? ~u : (u | 0x80000000u);
                            ldg[slot] = ((unsigned long long)u << 28) | (unsigned long long)jc1;
                        }
                    }
                    cnt += __popc(sub1);
                    unsigned long long m2 = __ballot(hit2);
                    unsigned sub2 = (unsigned)((m2 >> gsh) & 0xFFFFull);
                    if (hit2) {
                        int slot = cnt + __popc(sub2 & ((1u << l16) - 1u));
                        if (slot < CAPG) {
                            unsigned u = __float_as_uint(d2);
                            u = (u & 0x80000000u) ? ~u : (u | 0x80000000u);
                            ldg[slot] = ((unsigned long long)u << 28) | (unsigned long long)jc2;
                        }
                    }
                    cnt += __popc(sub2);
                }
            }
        }
        bool bad = active && (cnt < KNN || cnt > CAPG);
        if (__ballot(bad) == 0ULL) break;         // wave-uniform exit
        active = bad;
        if (active) r2 = (cnt < KNN) ? r2 * 1.6f : r2 * 0.82f;
    }

    // fill orig-idx field (bits 14..27) so u64 order == lex (d, orig idx)
    for (int k = l16; k < cnt; k += 16) {
        unsigned long long key = ldg[k];
        int jc = (int)(key & 0x3FFFull);
        ldg[k] = (key & ~0x0FFFFFFFull) | ((unsigned long long)Ob[jc] << 14) | (unsigned long long)jc;
    }
    __syncthreads();

    // ---- stable top-30: rank by u64 key (keys unique) ----
    const double qx = (double)qp.x, qy = (double)qp.y, qz = (double)qp.z;
    double sx = 0.0, sy = 0.0, sz = 0.0;
    double sxx = 0.0, sxy = 0.0, sxz = 0.0, syy = 0.0, syz = 0.0, szz = 0.0;

    for (int k = l16; k < cnt; k += 16) {
        unsigned long long key = ldg[k];
        int rank = 0;
        for (int u = 0; u < cnt; ++u) rank += (ldg[u] < key) ? 1 : 0;
        if (rank < KNN) {                         // exactly 30 survivors
            float4 p = P[(int)(key & 0x3FFFull)];
            double ax = (double)p.x - qx, ay = (double)p.y - qy, az = (double)p.z - qz;
            sx += ax; sy += ay; sz += az;
            sxx = fma(ax, ax, sxx); sxy = fma(ax, ay, sxy); sxz = fma(ax, az, sxz);
            syy = fma(ay, ay, syy); syz = fma(ay, az, syz); szz = fma(az, az, szz);
        }
    }

    #pragma unroll
    for (int off = 1; off < 16; off <<= 1) {
        sx  += __shfl_xor(sx,  off, 16); sy  += __shfl_xor(sy,  off, 16); sz  += __shfl_xor(sz,  off, 16);
        sxx += __shfl_xor(sxx, off, 16); sxy += __shfl_xor(sxy, off, 16); sxz += __shfl_xor(sxz, off, 16);
        syy += __shfl_xor(syy, off, 16); syz += __shfl_xor(syz, off, 16); szz += __shfl_xor(szz, off, 16);
    }

    if (l16 == 0) {
        const double kinv = 1.0 / (double)KNN;
        double m00 = sxx - sx * sx * kinv;
        double m11 = syy - sy * sy * kinv;
        double m22 = szz - sz * sz * kinv;
        double m01 = sxy - sx * sy * kinv;
        double m02 = sxz - sx * sz * kinv;
        double m12 = syz - sy * sz * kinv;

        double nx = 1.0, ny = 0.0, nz = 0.0;
        double q3 = (m00 + m11 + m22) / 3.0;
        double p1 = m01 * m01 + m02 * m02 + m12 * m12;
        double d00 = m00 - q3, d11 = m11 - q3, d22 = m22 - q3;
        double p2 = d00 * d00 + d11 * d11 + d22 * d22 + 2.0 * p1;
        if (p2 > 1e-280) {
            double pp = sqrt(p2 / 6.0);
            double ip = 1.0 / pp;
            double b00 = d00 * ip, b11 = d11 * ip, b22 = d22 * ip;
            double b01 = m01 * ip, b02 = m02 * ip, b12 = m12 * ip;
            double detB = b00 * (b11 * b22 - b12 * b12)
                        - b01 * (b01 * b22 - b12 * b02)
                        + b02 * (b01 * b12 - b11 * b02);
            double rr = 0.5 * detB;
            rr = rr < -1.0 ? -1.0 : (rr > 1.0 ? 1.0 : rr);
            double phi = acos(rr) / 3.0;
            double lam = q3 + 2.0 * pp * cos(phi + 2.0943951023931953); // smallest eig
            double a00 = m00 - lam, a11 = m11 - lam, a22 = m22 - lam;
            double v0x = m01 * m12 - m02 * a11, v0y = m02 * m01 - a00 * m12, v0z = a00 * a11 - m01 * m01;
            double v1x = m01 * a22 - m02 * m12, v1y = m02 * m02 - a00 * a22, v1z = a00 * m12 - m01 * m02;
            double v2x = a11 * a22 - m12 * m12, v2y = m12 * m02 - m01 * a22, v2z = m01 * m12 - a11 * m02;
            double n0 = v0x * v0x + v0y * v0y + v0z * v0z;
            double n1 = v1x * v1x + v1y * v1y + v1z * v1z;
            double n2 = v2x * v2x + v2y * v2y + v2z * v2z;
            double bx = v0x, by = v0y, bz = v0z, bn = n0;
            if (n1 > bn) { bx = v1x; by = v1y; bz = v1z; bn = n1; }
            if (n2 > bn) { bx = v2x; by = v2y; bz = v2z; bn = n2; }
            if (bn > 1e-280) {
                double inv = 1.0 / sqrt(bn);
                nx = bx * inv; ny = by * inv; nz = bz * inv;
            }
        }
        double dq = -(qx * nx + qy * ny + qz * nz);
        if (dq < 0.0) { nx = -nx; ny = -ny; nz = -nz; }

        float* ob = out + (size_t)b * 6 * N_PTS;
        ob[3 * N_PTS + oi] = (float)nx;
        ob[4 * N_PTS + oi] = (float)ny;
        ob[5 * N_PTS + oi] = (float)nz;
    }
}

// ---------------------------------------------------------------------------
extern "C" void kernel_launch(void* const* d_in, const int* in_sizes, int n_in,
                              void* d_out, int out_size, void* d_ws, size_t ws_size,
                              hipStream_t stream) {
    const float* x = (const float*)d_in[0];
    float* out = (float*)d_out;
    char* ws = (char*)d_ws;
    float4* S    = (float4*)(ws);                 // 512 KB
    int*    O    = (int*)(ws + 524288);           // 128 KB
    int*    bsta = (int*)(ws + 655360);           // 4*4097*4 = 65552 B

    prep_kernel<<<dim3(4), dim3(1024), 0, stream>>>(x, S, O, bsta, out);
    knn_normal_kernel<<<dim3(32768 / GROUPS), dim3(BLOCK), 0, stream>>>(S, O, bsta, out);
}